// Round 5
// baseline (171.815 us; speedup 1.0000x reference)
//
#include <hip/hip_runtime.h>

#define NEG (-1e30f)

// Problem dims (fixed by setup_inputs): B=16, TXT=128, MEL=512, NM=80
#define B_   16
#define TXT_ 128
#define MEL_ 512
#define NM_  80
#define IT_  8     // i-rows per lp block

// ---------------------------------------------------------------------------
// Kernel 1: log_prob_matrix, 8 i-rows per block, coalesced-only stores.
//   (x-mu)^2 * w + lv  ==  w*x^2 + b*x + c,  w=exp(-lv), b=-2*mu*w,
//   c = mu^2*w + lv  (c summed over n once per i).
// Writes lp twice: to d_out+1 (output, only 4B-aligned) and to d_ws (16B-
// aligned copy the scan can float4-load).
// NOTE: IT_*NM_ = 640 > blockDim 512 -> LDS fill must be a strided loop.
// ---------------------------------------------------------------------------
__global__ __launch_bounds__(512) void lp_kernel(
    const float* __restrict__ mu_logvar,  // (B, TXT, 2*NM)
    const float* __restrict__ melspec,    // (B, NM, MEL)
    float* __restrict__ lp_out,           // (B, TXT, MEL)  = d_out + 1
    float* __restrict__ lp_ws,            // (B, TXT, MEL)  aligned copy in ws
    float* __restrict__ out0)             // d_out[0]
{
    const int i0 = blockIdx.x * IT_;   // 0,8,...,120
    const int b  = blockIdx.y;
    const int t  = threadIdx.x;        // 0..511

    __shared__ float2 s_wb[IT_][NM_];     // (w, b) per (i,n)
    __shared__ float  s_cp[IT_ * NM_];    // per-(i,n) c, reduced below
    __shared__ float  s_cc[IT_];          // per-i sum of c

    for (int u = t; u < IT_ * NM_; u += 512) {
        int ii = u / NM_;
        int n  = u - ii * NM_;
        const float* row = mu_logvar + (size_t)(b * TXT_ + i0 + ii) * (2 * NM_);
        float mu = row[n];
        float lv = row[NM_ + n];
        float w  = __expf(-lv);
        s_wb[ii][n] = make_float2(w, -2.f * mu * w);
        s_cp[u]     = mu * mu * w + lv;
    }
    __syncthreads();
    if (t < IT_) {
        float c = 0.f;
        #pragma unroll
        for (int n = 0; n < NM_; ++n) c += s_cp[t * NM_ + n];
        s_cc[t] = c;
    }
    __syncthreads();

    const float* xcol = melspec + (size_t)b * NM_ * MEL_ + t;
    float acc[IT_];
    #pragma unroll
    for (int ii = 0; ii < IT_; ++ii) acc[ii] = 0.f;

    #pragma unroll 4
    for (int n = 0; n < NM_; ++n) {
        float x  = xcol[(size_t)n * MEL_];
        float x2 = x * x;
        #pragma unroll
        for (int ii = 0; ii < IT_; ++ii) {
            float2 wb = s_wb[ii][n];
            acc[ii] = fmaf(wb.x, x2, fmaf(wb.y, x, acc[ii]));
        }
    }

    const size_t rowbase = ((size_t)(b * TXT_ + i0)) * MEL_ + t;
    #pragma unroll
    for (int ii = 0; ii < IT_; ++ii) {
        float res = (-0.5f / (float)NM_) * (acc[ii] + s_cc[ii]);
        lp_out[rowbase + (size_t)ii * MEL_] = res;
        lp_ws [rowbase + (size_t)ii * MEL_] = res;
    }

    if (i0 == 0 && b == 0 && t == 0) *out0 = 0.f;
}

// ---------------------------------------------------------------------------
// Kernel 2: skewed-systolic monotonic-alignment scan. One wave per batch.
// Lane l owns columns j0=2l, j1=2l+1 and computes step t = d - 4*l at
// iteration d. Boundary alpha[t-1][2l-1] is lane l-1's a1-state shuffled
// 4 iterations earlier (4-entry register delay ring r[]) -> ds_bpermute
// latency is OFF the critical path. lp loads are per-lane float4 streams.
// R5 change: buffer depth 3 -> 6 (NBUF), unroll 12 -> 24, so refills lead
// consumption by 21 iterations (~1300 cyc at the predicted ~60 cyc/iter) --
// enough to cover L3/HBM-miss latency (~600-900 cyc) that R4's 8-iteration
// lead could not (R4: 255 cyc/iter, VALUBusy 0.95%).
// Pre-start lanes (t<1) self-absorb: -1e30 + anything stays -1e30 in fp32.
// Post-end corruption is harmless: consumers strictly lag producers; each
// lane snapshots its own result at t == Tend-1.
// ---------------------------------------------------------------------------
__device__ __forceinline__ float laexp(float a, float b) {
    float m = fmaxf(a, b);
    float d = fminf(a, b) - m;               // <= 0; exp underflows safely
    return m + __logf(1.f + __expf(d));
}
__device__ __forceinline__ float getc(const float4& v, int c) {
    switch (c & 3) { case 0: return v.x; case 1: return v.y;
                     case 2: return v.z; default: return v.w; }
}

#define NBUF_ 6
#define UNR_  (4 * NBUF_)   // 24

__global__ __launch_bounds__(64) void scan_kernel(
    const float* __restrict__ lp,          // aligned copy (B, TXT, MEL)
    const int* __restrict__ text_len, const int* __restrict__ mel_len,
    float* __restrict__ out0)
{
    const int b = blockIdx.x;
    const int l = threadIdx.x;
    const float* base = lp + (size_t)b * TXT_ * MEL_;
    const int Tend = mel_len[b], TendM1 = Tend - 1;   // Tend in [256,512]

    const float* row0 = base + (size_t)(2 * l) * MEL_;   // j0 row (16B aligned)
    const float* row1 = row0 + MEL_;                     // j1 row

    float lp00 = base[0];
    float a0 = (l == 0) ? lp00 : NEG;   // alpha[0][j0]
    float a1 = NEG;                     // alpha[0][j1]
    float fin0 = NEG, fin1 = NEG;

    int t_cur = 1 - 4 * l;              // t at d=1
    int t_pf  = 4 * NBUF_ - 4 * l;      // next prefetch block start

    float4 q0[NBUF_], q1[NBUF_];        // deep-buffered lp rows j0/j1
    #pragma unroll
    for (int s = 0; s < NBUF_; ++s) {
        int tc = min(max(4 * s - 4 * l, 0), MEL_ - 4);
        q0[s] = *(const float4*)(row0 + tc);
        q1[s] = *(const float4*)(row1 + tc);
    }
    float r[4] = {NEG, NEG, NEG, NEG};  // boundary delay ring (depth 4)

    const int D = TendM1 + 4 * 63;      // lane 63 finishes t=TendM1 here
    for (int d0 = 1; d0 <= D; d0 += UNR_) {
        #pragma unroll
        for (int k = 0; k < UNR_; ++k) {
            const int slot = ((k + 1) >> 2) % NBUF_;   // folds under unroll
            const int cmp_ = (k + 1) & 3;
            // consume boundary shuffled 4 iterations ago, then refill ring
            float bnd = (l == 0) ? NEG : r[cmp_];      // r index == d&3
            r[cmp_] = __shfl_up(a1, 1);                // state at start of iter
            float lpv0 = getc(q0[slot], cmp_);
            float lpv1 = getc(q1[slot], cmp_);
            float na0 = laexp(a0, bnd) + lpv0;         // alpha[t][j0]
            float na1 = laexp(a1, a0)  + lpv1;         // alpha[t][j1]
            bool hit = (t_cur == TendM1);
            fin0 = hit ? na0 : fin0;
            fin1 = hit ? na1 : fin1;
            a0 = na0; a1 = na1;
            ++t_cur;
            if (cmp_ == 3) {                           // refill just-drained slot
                int tc = min(max(t_pf, 0), MEL_ - 4);
                q0[slot] = *(const float4*)(row0 + tc);
                q1[slot] = *(const float4*)(row1 + tc);
                t_pf += 4;
            }
        }
    }

    int jstar = text_len[b] - 1;                   // in [63,127]
    float v   = (jstar & 1) ? fin1 : fin0;
    float val = __shfl(v, jstar >> 1);
    if (l == 0) atomicAdd(out0, -(val / (float)Tend) * (1.f / (float)B_));
}

// ---------------------------------------------------------------------------
extern "C" void kernel_launch(void* const* d_in, const int* in_sizes, int n_in,
                              void* d_out, int out_size, void* d_ws, size_t ws_size,
                              hipStream_t stream) {
    const float* mu_logvar = (const float*)d_in[0];
    const float* melspec   = (const float*)d_in[1];
    const int*   text_len  = (const int*)d_in[2];
    const int*   mel_len   = (const int*)d_in[3];

    float* out    = (float*)d_out;      // out[0] = mdn_loss, out[1..] = lp
    float* lp_out = out + 1;
    float* lp_ws  = (float*)d_ws;       // 16B-aligned lp copy (4 MB)

    dim3 g1(TXT_ / IT_, B_);
    lp_kernel<<<g1, MEL_, 0, stream>>>(mu_logvar, melspec, lp_out, lp_ws, out);
    scan_kernel<<<B_, 64, 0, stream>>>(lp_ws, text_len, mel_len, out);
}